// Round 1
// baseline (508.667 us; speedup 1.0000x reference)
//
#include <hip/hip_runtime.h>
#include <stdint.h>

// ---------- types & helpers ----------
typedef short bf16x8 __attribute__((ext_vector_type(8)));
typedef float f32x4 __attribute__((ext_vector_type(4)));

__device__ __forceinline__ float b2f(uint32_t h) {
    return __builtin_bit_cast(float, h << 16);
}
__device__ __forceinline__ uint16_t f2b(float f) {
    uint32_t u = __builtin_bit_cast(uint32_t, f);
    return (uint16_t)((u + 0x7fffu + ((u >> 16) & 1u)) >> 16);
}
__device__ __forceinline__ uint32_t mulpair(uint32_t a, uint32_t b) {
    uint32_t lo = f2b(b2f(a & 0xffffu) * b2f(b & 0xffffu));
    uint32_t hi = f2b(b2f(a >> 16) * b2f(b >> 16));
    return lo | (hi << 16);
}

__device__ __forceinline__ void gll16(const void* g, void* l) {
    __builtin_amdgcn_global_load_lds(
        (const __attribute__((address_space(1))) uint32_t*)(uintptr_t)g,
        (__attribute__((address_space(3))) uint32_t*)(uint32_t)(uintptr_t)l,
        16, 0, 0);
}

// ---------- fp32 -> bf16 convert (x) ----------
__global__ __launch_bounds__(256) void cvt_f32_bf16(const float4* __restrict__ in,
                                                    uint2* __restrict__ out, int nvec) {
    int i = blockIdx.x * 256 + threadIdx.x;
    if (i >= nvec) return;
    float4 v = in[i];
    uint2 o;
    o.x = (uint32_t)f2b(v.x) | ((uint32_t)f2b(v.y) << 16);
    o.y = (uint32_t)f2b(v.z) | ((uint32_t)f2b(v.w) << 16);
    out[i] = o;
}

// ---------- gate: ql *= qr (bf16, in place) ----------
__global__ __launch_bounds__(256) void gate_mul(uint2* __restrict__ q,
                                                const uint2* __restrict__ r, int nvec) {
    int i = blockIdx.x * 256 + threadIdx.x;
    if (i >= nvec) return;
    uint2 a = q[i], b = r[i];
    uint2 o;
    o.x = mulpair(a.x, b.x);
    o.y = mulpair(a.y, b.y);
    q[i] = o;
}

// ---------- weight transpose: W[1024][1024] f32 -> Wt[e][d] bf16 ----------
struct Ptr4 { const float* p[4]; };

__global__ __launch_bounds__(256) void tr_w(Ptr4 wp, uint16_t* __restrict__ out) {
    const float* in = wp.p[blockIdx.z];
    uint16_t* o = out + (size_t)blockIdx.z * 1048576;
    __shared__ uint16_t tile[64][68];
    int t = threadIdx.x;
    int r0 = blockIdx.y * 64, c0 = blockIdx.x * 64;
    for (int p = 0; p < 4; p++) {
        int row = p * 16 + (t >> 4);
        int c4 = (t & 15) * 4;
        float4 v = *(const float4*)&in[(size_t)(r0 + row) * 1024 + c0 + c4];
        tile[row][c4 + 0] = f2b(v.x);
        tile[row][c4 + 1] = f2b(v.y);
        tile[row][c4 + 2] = f2b(v.z);
        tile[row][c4 + 3] = f2b(v.w);
    }
    __syncthreads();
    for (int p = 0; p < 4; p++) {
        int a = p * 16 + (t >> 4);      // out row within tile (global col c0+a)
        int b4 = (t & 15) * 4;
        uint32_t x0 = tile[b4 + 0][a], x1 = tile[b4 + 1][a];
        uint32_t x2 = tile[b4 + 2][a], x3 = tile[b4 + 3][a];
        uint2 pk;
        pk.x = x0 | (x1 << 16);
        pk.y = x2 | (x3 << 16);
        *(uint2*)&o[(size_t)(c0 + a) * 1024 + r0 + b4] = pk;
    }
}

// ---------- bf16 transpose per batch: in [4096][1024] -> out [1024][4096] ----------
__global__ __launch_bounds__(256) void tr_kv(const uint16_t* __restrict__ in,
                                             uint16_t* __restrict__ out) {
    const uint16_t* ib = in + (size_t)blockIdx.z * (4096 * 1024);
    uint16_t* ob = out + (size_t)blockIdx.z * (1024 * 4096);
    __shared__ uint16_t tile[64][68];
    int t = threadIdx.x;
    int r0 = blockIdx.y * 64, c0 = blockIdx.x * 64;
    for (int p = 0; p < 4; p++) {
        int row = p * 16 + (t >> 4);
        int c4 = (t & 15) * 4;
        uint2 v = *(const uint2*)&ib[(size_t)(r0 + row) * 1024 + c0 + c4];
        tile[row][c4 + 0] = (uint16_t)(v.x & 0xffffu);
        tile[row][c4 + 1] = (uint16_t)(v.x >> 16);
        tile[row][c4 + 2] = (uint16_t)(v.y & 0xffffu);
        tile[row][c4 + 3] = (uint16_t)(v.y >> 16);
    }
    __syncthreads();
    for (int p = 0; p < 4; p++) {
        int a = p * 16 + (t >> 4);      // global col c0+a -> out row
        int b4 = (t & 15) * 4;
        uint32_t x0 = tile[b4 + 0][a], x1 = tile[b4 + 1][a];
        uint32_t x2 = tile[b4 + 2][a], x3 = tile[b4 + 3][a];
        uint2 pk;
        pk.x = x0 | (x1 << 16);
        pk.y = x2 | (x3 << 16);
        *(uint2*)&ob[(size_t)(c0 + a) * 4096 + r0 + b4] = pk;
    }
}

// ---------- m97-style bt-GEMM: C[M][N] = A[M][K] * Bt[N][K]^T, bf16 in, fp32 acc ----------
// grid: (N/128, M/128, Z). 256 threads = 4 waves, each wave does 64x64.
template <int OUT_BF16>
__global__ __launch_bounds__(256) void gemm_bt(const uint16_t* __restrict__ A,
                                               const uint16_t* __restrict__ Bt,
                                               void* __restrict__ C,
                                               int K, int ldc,
                                               long long sA, long long sB, long long sC) {
    const uint16_t* Ab = A + (size_t)blockIdx.z * sA;
    const uint16_t* Bb = Bt + (size_t)blockIdx.z * sB;

    __shared__ uint16_t lA[128 * 32];
    __shared__ uint16_t lB[128 * 32];

    const int t = threadIdx.x;
    const int wave = t >> 6;
    const int lane = t & 63;
    const int m0 = blockIdx.y * 128;
    const int n0 = blockIdx.x * 128;
    const int wm = (wave >> 1) * 64;
    const int wn = (wave & 1) * 64;

    // staging: chunk c = t + j*256 covers 16B at LDS elt offset c*8
    const uint16_t* gA0 = Ab + (size_t)(m0 + (t >> 2)) * K + (t & 3) * 8;
    const uint16_t* gB0 = Bb + (size_t)(n0 + (t >> 2)) * K + (t & 3) * 8;
    uint16_t* lA0 = lA + wave * 512;
    uint16_t* lA1 = lA + 2048 + wave * 512;
    uint16_t* lB0 = lB + wave * 512;
    uint16_t* lB1 = lB + 2048 + wave * 512;

    f32x4 acc[4][4] = {};

    const int arow = wm + (lane & 15);
    const int brow = wn + (lane & 15);
    const int koff = (lane >> 4) * 8;

    for (int k0 = 0; k0 < K; k0 += 32) {
        __syncthreads();                       // previous iter done reading LDS
        gll16(gA0 + k0, lA0);
        gll16(gA0 + (size_t)64 * K + k0, lA1);
        gll16(gB0 + k0, lB0);
        gll16(gB0 + (size_t)64 * K + k0, lB1);
        __syncthreads();                       // vmcnt(0) drain + barrier

        bf16x8 af[4], bfr[4];
#pragma unroll
        for (int i = 0; i < 4; i++)
            af[i] = *(const bf16x8*)&lA[(arow + i * 16) * 32 + koff];
#pragma unroll
        for (int i = 0; i < 4; i++)
            bfr[i] = *(const bf16x8*)&lB[(brow + i * 16) * 32 + koff];
#pragma unroll
        for (int i = 0; i < 4; i++)
#pragma unroll
            for (int j = 0; j < 4; j++)
                acc[i][j] = __builtin_amdgcn_mfma_f32_16x16x32_bf16(af[i], bfr[j],
                                                                    acc[i][j], 0, 0, 0);
    }

    // epilogue: C/D layout col=lane&15, row=(lane>>4)*4+reg
    const int crow = m0 + wm + (lane >> 4) * 4;
    const int ccol = n0 + wn + (lane & 15);
    if (OUT_BF16) {
        uint16_t* Cb = (uint16_t*)C + (size_t)blockIdx.z * sC;
#pragma unroll
        for (int i = 0; i < 4; i++)
#pragma unroll
            for (int j = 0; j < 4; j++)
#pragma unroll
                for (int r = 0; r < 4; r++)
                    Cb[(size_t)(crow + i * 16 + r) * ldc + ccol + j * 16] = f2b(acc[i][j][r]);
    } else {
        float* Cb = (float*)C + (size_t)blockIdx.z * sC;
#pragma unroll
        for (int i = 0; i < 4; i++)
#pragma unroll
            for (int j = 0; j < 4; j++)
#pragma unroll
                for (int r = 0; r < 4; r++)
                    Cb[(size_t)(crow + i * 16 + r) * ldc + ccol + j * 16] = acc[i][j][r];
    }
}

// ---------- launch ----------
extern "C" void kernel_launch(void* const* d_in, const int* in_sizes, int n_in,
                              void* d_out, int out_size, void* d_ws, size_t ws_size,
                              hipStream_t stream) {
    const float* x = (const float*)d_in[0];

    uint16_t* ws = (uint16_t*)d_ws;
    uint16_t* xb   = ws;                                // 16,777,216 elts (32MB)
    uint16_t* Wt   = ws + 16777216;                     // 4,194,304 elts (8MB)
    uint16_t* proj = ws + 16777216 + 4194304;           // 4 x 16,777,216 elts (128MB)
    uint16_t* QL = proj;
    uint16_t* QR = proj + (size_t)1 * 16777216;
    uint16_t* Kp = proj + (size_t)2 * 16777216;
    uint16_t* Vp = proj + (size_t)3 * 16777216;
    uint16_t* KT  = QR;   // QR dead after gate
    uint16_t* VT  = xb;   // xb dead after projections
    uint16_t* kvT = Wt;   // Wt dead after projections

    // 1. x -> bf16
    cvt_f32_bf16<<<16384, 256, 0, stream>>>((const float4*)x, (uint2*)xb, 4194304);

    // 2. weights -> transposed bf16
    Ptr4 wp;
    wp.p[0] = (const float*)d_in[1];
    wp.p[1] = (const float*)d_in[2];
    wp.p[2] = (const float*)d_in[3];
    wp.p[3] = (const float*)d_in[4];
    tr_w<<<dim3(16, 16, 4), 256, 0, stream>>>(wp, Wt);

    // 3. projections: proj[z] = xb @ Wt[z]^T   (M=16384, N=1024, K=1024)
    gemm_bt<1><<<dim3(8, 128, 4), 256, 0, stream>>>(xb, Wt, proj, 1024, 1024,
                                                    0LL, 1048576LL, 16777216LL);

    // 4. query = QL * QR (in place into QL)
    gate_mul<<<16384, 256, 0, stream>>>((uint2*)QL, (const uint2*)QR, 4194304);

    // 5. transpose K, V per batch -> [d][n]
    tr_kv<<<dim3(16, 64, 4), 256, 0, stream>>>(Kp, KT);
    tr_kv<<<dim3(16, 64, 4), 256, 0, stream>>>(Vp, VT);

    // 6. kvT[b][e][d] = sum_n VT[e][n] * KT[d][n]   (M=N=1024, K=4096)
    gemm_bt<1><<<dim3(8, 8, 4), 256, 0, stream>>>(VT, KT, kvT, 4096, 1024,
                                                  4194304LL, 4194304LL, 1048576LL);

    // 7. out[b][n][e] = sum_d query[n][d] * kvT[e][d]  (M=4096, N=1024, K=1024), fp32 out
    gemm_bt<0><<<dim3(8, 32, 4), 256, 0, stream>>>(QL, kvT, d_out, 1024, 1024,
                                                   4194304LL, 1048576LL, 4194304LL);
}

// Round 2
// 407.426 us; speedup vs baseline: 1.2485x; 1.2485x over previous
//
#include <hip/hip_runtime.h>
#include <stdint.h>

// ---------- types & helpers ----------
typedef short bf16x8 __attribute__((ext_vector_type(8)));
typedef float f32x4 __attribute__((ext_vector_type(4)));

__device__ __forceinline__ float b2f(uint32_t h) {
    return __builtin_bit_cast(float, h << 16);
}
__device__ __forceinline__ uint16_t f2b(float f) {
    uint32_t u = __builtin_bit_cast(uint32_t, f);
    return (uint16_t)((u + 0x7fffu + ((u >> 16) & 1u)) >> 16);
}

__device__ __forceinline__ void gll16(const void* g, void* l) {
    __builtin_amdgcn_global_load_lds(
        (const __attribute__((address_space(1))) uint32_t*)(uintptr_t)g,
        (__attribute__((address_space(3))) uint32_t*)(uint32_t)(uintptr_t)l,
        16, 0, 0);
}

// ---------- fp32 -> bf16 convert (x) ----------
__global__ __launch_bounds__(256) void cvt_f32_bf16(const float4* __restrict__ in,
                                                    uint2* __restrict__ out, int nvec) {
    int i = blockIdx.x * 256 + threadIdx.x;
    if (i >= nvec) return;
    float4 v = in[i];
    uint2 o;
    o.x = (uint32_t)f2b(v.x) | ((uint32_t)f2b(v.y) << 16);
    o.y = (uint32_t)f2b(v.z) | ((uint32_t)f2b(v.w) << 16);
    out[i] = o;
}

// ---------- weight transpose: W[1024][1024] f32 -> Wt[e][d] bf16 ----------
struct Ptr4 { const float* p[4]; };

__global__ __launch_bounds__(256) void tr_w(Ptr4 wp, uint16_t* __restrict__ out) {
    const float* in = wp.p[blockIdx.z];
    uint16_t* o = out + (size_t)blockIdx.z * 1048576;
    __shared__ uint16_t tile[64][68];
    int t = threadIdx.x;
    int r0 = blockIdx.y * 64, c0 = blockIdx.x * 64;
    for (int p = 0; p < 4; p++) {
        int row = p * 16 + (t >> 4);
        int c4 = (t & 15) * 4;
        float4 v = *(const float4*)&in[(size_t)(r0 + row) * 1024 + c0 + c4];
        tile[row][c4 + 0] = f2b(v.x);
        tile[row][c4 + 1] = f2b(v.y);
        tile[row][c4 + 2] = f2b(v.z);
        tile[row][c4 + 3] = f2b(v.w);
    }
    __syncthreads();
    for (int p = 0; p < 4; p++) {
        int a = p * 16 + (t >> 4);
        int b4 = (t & 15) * 4;
        uint32_t x0 = tile[b4 + 0][a], x1 = tile[b4 + 1][a];
        uint32_t x2 = tile[b4 + 2][a], x3 = tile[b4 + 3][a];
        uint2 pk;
        pk.x = x0 | (x1 << 16);
        pk.y = x2 | (x3 << 16);
        *(uint2*)&o[(size_t)(c0 + a) * 1024 + r0 + b4] = pk;
    }
}

// ---------- fused dual-B GEMM: acc1 = A@B1^T, acc2 = A@B2^T over 128x128 tile ----------
// MODE 0 (GATE): write f2b(acc1*acc2) to C [m][n] bf16 (n-major, ld 1024)
// MODE 1 (KVT):  write acc1 -> C1 and acc2 -> C2 TRANSPOSED [n][m] bf16, per-batch
//                (batch = m0>>12, ld 4096, batch stride 4194304)
union SmemU {
    struct { uint16_t lA[128 * 32]; uint16_t lB1[128 * 32]; uint16_t lB2[128 * 32]; } s;
    uint16_t tr[4][64][68];
};

template <int MODE>
__global__ __launch_bounds__(256, 2) void proj2(const uint16_t* __restrict__ A,
                                                const uint16_t* __restrict__ B1,
                                                const uint16_t* __restrict__ B2,
                                                uint16_t* __restrict__ C1,
                                                uint16_t* __restrict__ C2) {
    __shared__ SmemU u;
    const int K = 1024;
    const int t = threadIdx.x;
    const int wave = t >> 6;
    const int lane = t & 63;
    const int m0 = blockIdx.y * 128;
    const int n0 = blockIdx.x * 128;
    const int wm = (wave >> 1) * 64;
    const int wn = (wave & 1) * 64;

    const uint16_t* gA0 = A + (size_t)(m0 + (t >> 2)) * K + (t & 3) * 8;
    const uint16_t* gB1 = B1 + (size_t)(n0 + (t >> 2)) * K + (t & 3) * 8;
    const uint16_t* gB2 = B2 + (size_t)(n0 + (t >> 2)) * K + (t & 3) * 8;
    uint16_t* lA0 = u.s.lA + wave * 512;
    uint16_t* lA1 = u.s.lA + 2048 + wave * 512;
    uint16_t* lB10 = u.s.lB1 + wave * 512;
    uint16_t* lB11 = u.s.lB1 + 2048 + wave * 512;
    uint16_t* lB20 = u.s.lB2 + wave * 512;
    uint16_t* lB21 = u.s.lB2 + 2048 + wave * 512;

    f32x4 acc1[4][4] = {};
    f32x4 acc2[4][4] = {};

    const int arow = wm + (lane & 15);
    const int brow = wn + (lane & 15);
    const int koff = (lane >> 4) * 8;

    for (int k0 = 0; k0 < K; k0 += 32) {
        __syncthreads();
        gll16(gA0 + k0, lA0);
        gll16(gA0 + (size_t)64 * K + k0, lA1);
        gll16(gB1 + k0, lB10);
        gll16(gB1 + (size_t)64 * K + k0, lB11);
        gll16(gB2 + k0, lB20);
        gll16(gB2 + (size_t)64 * K + k0, lB21);
        __syncthreads();

        bf16x8 af[4], b1f[4], b2f_[4];
#pragma unroll
        for (int i = 0; i < 4; i++)
            af[i] = *(const bf16x8*)&u.s.lA[(arow + i * 16) * 32 + koff];
#pragma unroll
        for (int i = 0; i < 4; i++)
            b1f[i] = *(const bf16x8*)&u.s.lB1[(brow + i * 16) * 32 + koff];
#pragma unroll
        for (int i = 0; i < 4; i++)
            b2f_[i] = *(const bf16x8*)&u.s.lB2[(brow + i * 16) * 32 + koff];
#pragma unroll
        for (int i = 0; i < 4; i++)
#pragma unroll
            for (int j = 0; j < 4; j++) {
                acc1[i][j] = __builtin_amdgcn_mfma_f32_16x16x32_bf16(af[i], b1f[i * 0 + j],
                                                                     acc1[i][j], 0, 0, 0);
                acc2[i][j] = __builtin_amdgcn_mfma_f32_16x16x32_bf16(af[i], b2f_[j],
                                                                     acc2[i][j], 0, 0, 0);
            }
    }

    if (MODE == 0) {
        // gate epilogue: C1[m][n] = bf16(acc1 * acc2)
        const int crow = m0 + wm + (lane >> 4) * 4;
        const int ccol = n0 + wn + (lane & 15);
#pragma unroll
        for (int i = 0; i < 4; i++)
#pragma unroll
            for (int j = 0; j < 4; j++)
#pragma unroll
                for (int r = 0; r < 4; r++) {
                    float g = acc1[i][j][r] * acc2[i][j][r];
                    C1[(size_t)(crow + i * 16 + r) * 1024 + ccol + j * 16] = f2b(g);
                }
    } else {
        // transposed epilogue via per-wave LDS scratch
        __syncthreads();  // all waves done reading lA/lB before overwrite
        const int bofs = (m0 >> 12) * 4194304;
        const int tok0 = (m0 & 4095) + wm;
        const int fbase = n0 + wn;
        uint16_t* outs[2] = {C1, C2};
        for (int s = 0; s < 2; s++) {
            f32x4(*acc)[4] = (s == 0) ? acc1 : acc2;
#pragma unroll
            for (int i = 0; i < 4; i++)
#pragma unroll
                for (int j = 0; j < 4; j++) {
                    int col = j * 16 + (lane & 15);
                    int row0 = i * 16 + (lane >> 4) * 4;
                    uint32_t lo = (uint32_t)f2b(acc[i][j][0]) | ((uint32_t)f2b(acc[i][j][1]) << 16);
                    uint32_t hi = (uint32_t)f2b(acc[i][j][2]) | ((uint32_t)f2b(acc[i][j][3]) << 16);
                    uint2 pk; pk.x = lo; pk.y = hi;
                    *(uint2*)&u.tr[wave][col][row0] = pk;
                }
            __builtin_amdgcn_s_waitcnt(0);  // drain LDS writes (intra-wave ordering safety)
            uint16_t* O = outs[s] + bofs;
#pragma unroll
            for (int dd = 0; dd < 16; dd++) {
                int f = dd * 4 + (lane >> 4);
                int t4 = (lane & 15) * 4;
                uint2 v = *(const uint2*)&u.tr[wave][f][t4];
                *(uint2*)&O[(size_t)(fbase + f) * 4096 + tok0 + t4] = v;
            }
            __builtin_amdgcn_s_waitcnt(0);
        }
    }
}

// ---------- single-B GEMM (m97 style), used for out GEMM ----------
template <int OUT_BF16>
__global__ __launch_bounds__(256) void gemm_bt(const uint16_t* __restrict__ A,
                                               const uint16_t* __restrict__ Bt,
                                               void* __restrict__ C,
                                               int K, int ldc,
                                               long long sA, long long sB, long long sC) {
    const uint16_t* Ab = A + (size_t)blockIdx.z * sA;
    const uint16_t* Bb = Bt + (size_t)blockIdx.z * sB;

    __shared__ uint16_t lA[128 * 32];
    __shared__ uint16_t lB[128 * 32];

    const int t = threadIdx.x;
    const int wave = t >> 6;
    const int lane = t & 63;
    const int m0 = blockIdx.y * 128;
    const int n0 = blockIdx.x * 128;
    const int wm = (wave >> 1) * 64;
    const int wn = (wave & 1) * 64;

    const uint16_t* gA0 = Ab + (size_t)(m0 + (t >> 2)) * K + (t & 3) * 8;
    const uint16_t* gB0 = Bb + (size_t)(n0 + (t >> 2)) * K + (t & 3) * 8;
    uint16_t* lA0 = lA + wave * 512;
    uint16_t* lA1 = lA + 2048 + wave * 512;
    uint16_t* lB0 = lB + wave * 512;
    uint16_t* lB1 = lB + 2048 + wave * 512;

    f32x4 acc[4][4] = {};

    const int arow = wm + (lane & 15);
    const int brow = wn + (lane & 15);
    const int koff = (lane >> 4) * 8;

    for (int k0 = 0; k0 < K; k0 += 32) {
        __syncthreads();
        gll16(gA0 + k0, lA0);
        gll16(gA0 + (size_t)64 * K + k0, lA1);
        gll16(gB0 + k0, lB0);
        gll16(gB0 + (size_t)64 * K + k0, lB1);
        __syncthreads();

        bf16x8 af[4], bfr[4];
#pragma unroll
        for (int i = 0; i < 4; i++)
            af[i] = *(const bf16x8*)&lA[(arow + i * 16) * 32 + koff];
#pragma unroll
        for (int i = 0; i < 4; i++)
            bfr[i] = *(const bf16x8*)&lB[(brow + i * 16) * 32 + koff];
#pragma unroll
        for (int i = 0; i < 4; i++)
#pragma unroll
            for (int j = 0; j < 4; j++)
                acc[i][j] = __builtin_amdgcn_mfma_f32_16x16x32_bf16(af[i], bfr[j],
                                                                    acc[i][j], 0, 0, 0);
    }

    const int crow = m0 + wm + (lane >> 4) * 4;
    const int ccol = n0 + wn + (lane & 15);
    if (OUT_BF16) {
        uint16_t* Cb = (uint16_t*)C + (size_t)blockIdx.z * sC;
#pragma unroll
        for (int i = 0; i < 4; i++)
#pragma unroll
            for (int j = 0; j < 4; j++)
#pragma unroll
                for (int r = 0; r < 4; r++)
                    Cb[(size_t)(crow + i * 16 + r) * ldc + ccol + j * 16] = f2b(acc[i][j][r]);
    } else {
        float* Cb = (float*)C + (size_t)blockIdx.z * sC;
#pragma unroll
        for (int i = 0; i < 4; i++)
#pragma unroll
            for (int j = 0; j < 4; j++)
#pragma unroll
                for (int r = 0; r < 4; r++)
                    Cb[(size_t)(crow + i * 16 + r) * ldc + ccol + j * 16] = acc[i][j][r];
    }
}

// ---------- split-K kv GEMM: P[z] = VT[b, :, ks*1024:(ks+1)*1024] @ KT[b,...]^T ----------
// z = batch*4 + ks; M=N=1024; row stride 4096; fp32 partial out.
__global__ __launch_bounds__(256) void gemm_kv_splitk(const uint16_t* __restrict__ VT,
                                                      const uint16_t* __restrict__ KT,
                                                      float* __restrict__ P) {
    const int z = blockIdx.z;
    const int batch = z >> 2, ks = z & 3;
    const uint16_t* Ab = VT + (size_t)batch * 4194304 + ks * 1024;
    const uint16_t* Bb = KT + (size_t)batch * 4194304 + ks * 1024;

    __shared__ uint16_t lA[128 * 32];
    __shared__ uint16_t lB[128 * 32];

    const int t = threadIdx.x;
    const int wave = t >> 6;
    const int lane = t & 63;
    const int m0 = blockIdx.y * 128;
    const int n0 = blockIdx.x * 128;
    const int wm = (wave >> 1) * 64;
    const int wn = (wave & 1) * 64;

    const uint16_t* gA0 = Ab + (size_t)(m0 + (t >> 2)) * 4096 + (t & 3) * 8;
    const uint16_t* gB0 = Bb + (size_t)(n0 + (t >> 2)) * 4096 + (t & 3) * 8;
    uint16_t* lA0 = lA + wave * 512;
    uint16_t* lA1 = lA + 2048 + wave * 512;
    uint16_t* lB0 = lB + wave * 512;
    uint16_t* lB1 = lB + 2048 + wave * 512;

    f32x4 acc[4][4] = {};

    const int arow = wm + (lane & 15);
    const int brow = wn + (lane & 15);
    const int koff = (lane >> 4) * 8;

    for (int k0 = 0; k0 < 1024; k0 += 32) {
        __syncthreads();
        gll16(gA0 + k0, lA0);
        gll16(gA0 + (size_t)64 * 4096 + k0, lA1);
        gll16(gB0 + k0, lB0);
        gll16(gB0 + (size_t)64 * 4096 + k0, lB1);
        __syncthreads();

        bf16x8 af[4], bfr[4];
#pragma unroll
        for (int i = 0; i < 4; i++)
            af[i] = *(const bf16x8*)&lA[(arow + i * 16) * 32 + koff];
#pragma unroll
        for (int i = 0; i < 4; i++)
            bfr[i] = *(const bf16x8*)&lB[(brow + i * 16) * 32 + koff];
#pragma unroll
        for (int i = 0; i < 4; i++)
#pragma unroll
            for (int j = 0; j < 4; j++)
                acc[i][j] = __builtin_amdgcn_mfma_f32_16x16x32_bf16(af[i], bfr[j],
                                                                    acc[i][j], 0, 0, 0);
    }

    float* Pb = P + (size_t)z * 1048576;
    const int crow = m0 + wm + (lane >> 4) * 4;
    const int ccol = n0 + wn + (lane & 15);
#pragma unroll
    for (int i = 0; i < 4; i++)
#pragma unroll
        for (int j = 0; j < 4; j++)
#pragma unroll
            for (int r = 0; r < 4; r++)
                Pb[(size_t)(crow + i * 16 + r) * 1024 + ccol + j * 16] = acc[i][j][r];
}

// ---------- reduce 4 fp32 partials -> bf16 kvT ----------
__global__ __launch_bounds__(256) void reduce_kv(const float4* __restrict__ P,
                                                 uint2* __restrict__ kvT) {
    int i = blockIdx.x * 256 + threadIdx.x;   // 0..1M (float4 units)
    int b = i >> 18;
    int r = i & 262143;
    const float4* base = P + (size_t)b * 1048576 + r;
    float4 s0 = base[0];
    float4 s1 = base[262144];
    float4 s2 = base[524288];
    float4 s3 = base[786432];
    float x = s0.x + s1.x + s2.x + s3.x;
    float y = s0.y + s1.y + s2.y + s3.y;
    float zz = s0.z + s1.z + s2.z + s3.z;
    float w = s0.w + s1.w + s2.w + s3.w;
    uint2 o;
    o.x = (uint32_t)f2b(x) | ((uint32_t)f2b(y) << 16);
    o.y = (uint32_t)f2b(zz) | ((uint32_t)f2b(w) << 16);
    kvT[i] = o;
}

// ---------- launch ----------
extern "C" void kernel_launch(void* const* d_in, const int* in_sizes, int n_in,
                              void* d_out, int out_size, void* d_ws, size_t ws_size,
                              hipStream_t stream) {
    const float* x = (const float*)d_in[0];

    uint16_t* ws = (uint16_t*)d_ws;
    // region A [0, 32M elems): xb first 16M; later kvP (16M floats)
    uint16_t* xb  = ws;
    float*    kvP = (float*)d_ws;
    uint16_t* Wt  = ws + 33554432;             // [32M, 36M)
    uint16_t* kvT = Wt;                        // reuses Wt after projections
    uint16_t* Q   = ws + 37748736;             // [36M, 52M)
    uint16_t* KT  = ws + 54525952;             // [52M, 68M)
    uint16_t* VT  = ws + 71303168;             // [68M, 84M)

    // 1. x -> bf16
    cvt_f32_bf16<<<16384, 256, 0, stream>>>((const float4*)x, (uint2*)xb, 4194304);

    // 2. weights -> transposed bf16 (concat: wql, wqr, wk, wv)
    Ptr4 wp;
    wp.p[0] = (const float*)d_in[1];
    wp.p[1] = (const float*)d_in[2];
    wp.p[2] = (const float*)d_in[3];
    wp.p[3] = (const float*)d_in[4];
    tr_w<<<dim3(16, 16, 4), 256, 0, stream>>>(wp, Wt);

    // 3. Q = (x@Wql^T) * (x@Wqr^T), fused gate
    proj2<0><<<dim3(8, 128), 256, 0, stream>>>(xb, Wt, Wt + 1048576, Q, nullptr);

    // 4. KT/VT = transposed projections (K first -> C1=KT, V -> C2=VT)
    proj2<1><<<dim3(8, 128), 256, 0, stream>>>(xb, Wt + 2097152, Wt + 3145728, KT, VT);

    // 5. kv partials: P[b*4+ks] = VT-slice @ KT-slice^T
    gemm_kv_splitk<<<dim3(8, 8, 16), 256, 0, stream>>>(VT, KT, kvP);

    // 6. reduce partials -> kvT bf16
    reduce_kv<<<4096, 256, 0, stream>>>((const float4*)kvP, (uint2*)kvT);

    // 7. out[b][n][e] = Q @ kvT^T, fp32 out
    gemm_bt<0><<<dim3(8, 32, 4), 256, 0, stream>>>(Q, kvT, d_out, 1024, 1024,
                                                   4194304LL, 1048576LL, 4194304LL);
}